// Round 6
// baseline (215.752 us; speedup 1.0000x reference)
//
#include <hip/hip_runtime.h>

#define KTOP 64
#define GX   32
#define NCELL (GX*GX)
#define CSF  3.2f
#define X0F  -51.2f
#define TR   256        // param rows staged per tile (per-wave LDS)

// Anti-contraction barrier: force f32 rounding points to match the reference.
#define BAR(x) asm volatile("" : "+v"(x))

// -------- binning helpers (f64, conservative margins; proven rounds 4-5) -----
__device__ inline void g_reach_cells(float s0, float s1, float s2,
                                     float m0, float m1,
                                     int& cx0, int& cx1, int& cy0, int& cy1,
                                     double& mux, double& muy, double& reach2)
{
    const double ss0 = (double)s0 * (double)s0 + 1e-8;
    const double ss1 = (double)s1 * (double)s1 + 1e-8;
    const double ss2 = (double)s2 * (double)s2 + 1e-8;
    double smax = ss0 > ss1 ? ss0 : ss1; smax = smax > ss2 ? smax : ss2;
    const double sum = ss0 + ss1 + ss2;
    reach2 = 9.0 * smax * sum * 1.0005 + 0.5;   // covers f32 d2/r2 rounding
    const double reach = sqrt(reach2);
    mux = (double)m0; muy = (double)m1;
    cx0 = (int)floor((mux - reach - (double)X0F) / (double)CSF);
    cx1 = (int)floor((mux + reach - (double)X0F) / (double)CSF);
    cy0 = (int)floor((muy - reach - (double)X0F) / (double)CSF);
    cy1 = (int)floor((muy + reach - (double)X0F) / (double)CSF);
    cx0 = cx0 < 0 ? 0 : cx0;  cy0 = cy0 < 0 ? 0 : cy0;
    cx1 = cx1 > GX-1 ? GX-1 : cx1;  cy1 = cy1 > GX-1 ? GX-1 : cy1;
}

__device__ inline bool cell_hits(int cx, int cy, double mux, double muy, double reach2)
{
    const double lx = (double)X0F + (double)cx * (double)CSF - 1e-3;
    const double hx = lx + (double)CSF + 2e-3;
    const double ly = (double)X0F + (double)cy * (double)CSF - 1e-3;
    const double hy = ly + (double)CSF + 2e-3;
    double dx = 0.0, dy = 0.0;
    if (mux < lx) dx = lx - mux; else if (mux > hx) dx = mux - hx;
    if (muy < ly) dy = ly - muy; else if (muy > hy) dy = muy - hy;
    return dx*dx + dy*dy <= reach2;
}

__device__ inline void q_center(int ix, int iy, int iz, float pc0, float pc1, float pc2,
                                float& qx, float& qy, float& qz)
{
    float tx = ((float)ix + 0.5f) * 0.2f; BAR(tx);
    float ty = ((float)iy + 0.5f) * 0.2f; BAR(ty);
    float tz = ((float)iz + 0.5f) * 0.2f; BAR(tz);
    qx = pc0 + tx;  qy = pc1 + ty;  qz = pc2 + tz;
}

__device__ inline int q_cell(float qx, float qy)
{
    int cx = (int)floorf((qx - X0F) * (1.0f / CSF));
    int cy = (int)floorf((qy - X0F) * (1.0f / CSF));
    cx = cx < 0 ? 0 : (cx > GX-1 ? GX-1 : cx);
    cy = cy < 0 ? 0 : (cy > GX-1 ? GX-1 : cy);
    return cy * GX + cx;
}

// -------- kernel 1: zero both counter arrays --------
__global__ __launch_bounds__(1024)
void k_zero(int* __restrict__ cnts)
{
    cnts[blockIdx.x * 1024 + threadIdx.x] = 0;
}

// -------- kernel 2: params + gaussian cell masks + counts; query centers + counts --------
__global__ __launch_bounds__(256)
void k_count(const float* __restrict__ mu, const float* __restrict__ scale,
             const int* __restrict__ vox, const float* __restrict__ pcr,
             float* __restrict__ params, unsigned long long* __restrict__ cellinfo,
             int* __restrict__ gcnt, int* __restrict__ qcnt,
             float* __restrict__ out, int N, int M, int GB)
{
    const int b = blockIdx.x;
    if (b < GB) {
        const int g = b * 256 + threadIdx.x;
        if (g >= N) return;
        const float s0 = scale[3*g+0], s1 = scale[3*g+1], s2 = scale[3*g+2];
        const float m0 = mu[3*g+0],    m1 = mu[3*g+1],    m2 = mu[3*g+2];
        // proven bit-exact f32 param derivation
        float s0s = s0 * s0; BAR(s0s);
        float s1s = s1 * s1; BAR(s1s);
        float s2s = s2 * s2; BAR(s2s);
        float d0 = s0s + 1e-8f;
        float d1 = s1s + 1e-8f;
        float dd2 = s2s + 1e-8f;
        float i0 = 1.0f / d0;
        float i1 = 1.0f / d1;
        float i2 = 1.0f / dd2;
        float mi0 = m0 * i0; BAR(mi0);
        float mi1 = m1 * i1; BAR(mi1);
        float mi2 = m2 * i2; BAR(mi2);
        float p0 = m0 * mi0; BAR(p0);
        float p1 = m1 * mi1; BAR(p1);
        float p2 = m2 * mi2; BAR(p2);
        float mt = (p0 + p1) + p2;
        float rs = (s0s + s1s) + s2s;
        float r2 = 9.0f * rs;
        *(float4*)&params[(size_t)g*8]     = make_float4(i0, i1, i2, mi0);
        *(float4*)&params[(size_t)g*8 + 4] = make_float4(mi1, mi2, mt, r2);

        int cx0, cx1, cy0, cy1; double mux, muy, reach2;
        g_reach_cells(s0, s1, s2, m0, m1, cx0, cx1, cy0, cy1, mux, muy, reach2);
        const int w = cx1 - cx0 + 1;
        unsigned long long mask = 0ull;
        for (int cy = cy0; cy <= cy1; ++cy)
            for (int cx = cx0; cx <= cx1; ++cx)
                if (cell_hits(cx, cy, mux, muy, reach2)) {
                    mask |= 1ull << ((cy - cy0) * w + (cx - cx0));
                    atomicAdd(&gcnt[cy*GX + cx], 1);
                }
        cellinfo[g] = mask | ((unsigned long long)w << 49)
                           | ((unsigned long long)cx0 << 54)
                           | ((unsigned long long)cy0 << 59);
    } else {
        const int q = (b - GB) * 256 + threadIdx.x;
        if (q >= M) return;
        int4 c = ((const int4*)vox)[q];   // (b, z, y, x)
        float qx, qy, qz;
        q_center(c.w, c.z, c.y, pcr[0], pcr[1], pcr[2], qx, qy, qz);
        out[3*(size_t)q + 0] = qx;
        out[3*(size_t)q + 1] = qy;
        out[3*(size_t)q + 2] = qz;
        atomicAdd(&qcnt[q_cell(qx, qy)], 1);
    }
}

// -------- kernel 3: both prefix sums in ONE wave (shfl scan, no barriers) ----
__global__ __launch_bounds__(64)
void k_prefix(const int* __restrict__ gcnt, const int* __restrict__ qcnt,
              int* __restrict__ goff, int* __restrict__ qoff,
              int* __restrict__ gcur, int* __restrict__ qcur)
{
    const int t = threadIdx.x;   // 16 cells per lane
    {
        int v[16], loc[16]; int s = 0;
        #pragma unroll
        for (int i = 0; i < 16; ++i) v[i] = gcnt[t*16 + i];
        #pragma unroll
        for (int i = 0; i < 16; ++i) { loc[i] = s; s += v[i]; }
        int x = s;
        #pragma unroll
        for (int off = 1; off < 64; off <<= 1) {
            int y = __shfl_up(x, off, 64);
            if (t >= off) x += y;
        }
        const int ex = x - s;
        #pragma unroll
        for (int i = 0; i < 16; ++i) {
            goff[t*16 + i] = ex + loc[i];
            gcur[t*16 + i] = ex + loc[i];
        }
        if (t == 63) goff[NCELL] = ex + s;
    }
    {
        int v[16], loc[16]; int s = 0;
        #pragma unroll
        for (int i = 0; i < 16; ++i) v[i] = qcnt[t*16 + i];
        #pragma unroll
        for (int i = 0; i < 16; ++i) { loc[i] = s; s += v[i]; }
        int x = s;
        #pragma unroll
        for (int off = 1; off < 64; off <<= 1) {
            int y = __shfl_up(x, off, 64);
            if (t >= off) x += y;
        }
        const int ex = x - s;
        #pragma unroll
        for (int i = 0; i < 16; ++i) {
            qoff[t*16 + i] = ex + loc[i];
            qcur[t*16 + i] = ex + loc[i];
        }
        if (t == 63) qoff[NCELL] = ex + s;
    }
}

// -------- kernel 4: scatter via precomputed masks (no f64 redo) --------
__global__ __launch_bounds__(256)
void k_scatter(const unsigned long long* __restrict__ cellinfo,
               const int* __restrict__ vox, const float* __restrict__ pcr,
               int* __restrict__ gcur, int* __restrict__ qcur,
               unsigned short* __restrict__ entries, int* __restrict__ qids,
               int N, int M, int GB)
{
    const int b = blockIdx.x;
    if (b < GB) {
        const int g = b * 256 + threadIdx.x;
        if (g >= N) return;
        unsigned long long ci = cellinfo[g];
        unsigned long long mask = ci & ((1ull << 49) - 1);
        const int w   = (int)((ci >> 49) & 31);
        const int cx0 = (int)((ci >> 54) & 31);
        const int cy0 = (int)((ci >> 59) & 31);
        while (mask) {
            const int bpos = __builtin_ctzll(mask);
            mask &= mask - 1;
            const int cy = cy0 + bpos / w;
            const int cx = cx0 + bpos % w;
            int pos = atomicAdd(&gcur[cy*GX + cx], 1);
            entries[pos] = (unsigned short)g;
        }
    } else {
        const int q = (b - GB) * 256 + threadIdx.x;
        if (q >= M) return;
        int4 c = ((const int4*)vox)[q];
        float qx, qy, qz;
        q_center(c.w, c.z, c.y, pcr[0], pcr[1], pcr[2], qx, qy, qz);
        int pos = atomicAdd(&qcur[q_cell(qx, qy)], 1);
        qids[pos] = q;
    }
}

// -------- kernel 5: one wave per cell; full list per lane; no merge ----------
__global__ __launch_bounds__(64)
void k_scan(const int* __restrict__ vox, const float* __restrict__ pcr,
            const float* __restrict__ params,
            const unsigned short* __restrict__ entries, const int* __restrict__ goff,
            const int* __restrict__ qids, const int* __restrict__ qoff,
            float* __restrict__ out, int M)
{
    __shared__ float Pa[TR][8];
    __shared__ int   Pg[TR];

    const int cell = blockIdx.x;
    const int l = threadIdx.x;
    const int qb = qoff[cell], qe = qoff[cell + 1];
    if (qb == qe) return;
    const int gb = goff[cell], ge = goff[cell + 1];
    const int L = ge - gb;

    const float pc0 = pcr[0], pc1 = pcr[1], pc2 = pcr[2];

    float* idxb = out + 3 * (size_t)M;
    float* wb   = idxb + (size_t)M * KTOP;
    float* mb   = wb   + (size_t)M * KTOP;

    for (int q0 = qb; q0 < qe; q0 += 64) {
        const int nq = (qe - q0 < 64) ? (qe - q0) : 64;
        const bool act = (l < nq);
        const int q = act ? qids[q0 + l] : 0;

        float qx = 0.f, qy = 0.f, qz = 0.f;
        if (act) {
            int4 c = ((const int4*)vox)[q];
            q_center(c.w, c.z, c.y, pc0, pc1, pc2, qx, qy, qz);
        }
        float qx2 = qx * qx; BAR(qx2);
        float qy2 = qy * qy; BAR(qy2);
        float qz2 = qz * qz; BAR(qz2);

        float key[KTOP];
        int   gi[KTOP];
        int   cnt = 0;

        for (int t0 = 0; t0 < L; t0 += TR) {
            const int rows = (L - t0 < TR) ? (L - t0) : TR;
            __syncthreads();   // single-wave barrier: orders LDS reuse, ~free
            for (int r = l; r < rows * 2; r += 64) {
                const int row = r >> 1, half = r & 1;
                const int g = entries[gb + t0 + row];
                float4 v = *(const float4*)&params[(size_t)g * 8 + half * 4];
                *(float4*)&Pa[row][half * 4] = v;
                if (half == 0) Pg[row] = g;
            }
            __syncthreads();

            if (act) {
                for (int i = 0; i < rows; ++i) {
                    const float4 pa = *(const float4*)&Pa[i][0];
                    const float4 pb = *(const float4*)&Pa[i][4];
                    // proven bit-exact d2 (rounds 2-5)
                    float t1 = __builtin_fmaf(qz2, pa.z, __builtin_fmaf(qy2, pa.y, qx2 * pa.x));
                    float t2 = __builtin_fmaf(qz,  pb.y, __builtin_fmaf(qy,  pb.x, qx  * pa.w));
                    const float d2v = (t1 - 2.0f * t2) + pb.z;
                    if (d2v <= pb.w) {
                        const int g = Pg[i];
                        int j;
                        if (cnt < KTOP) {
                            j = cnt++;
                        } else {
                            const float lk = key[KTOP-1]; const int lg = gi[KTOP-1];
                            if (d2v < lk || (d2v == lk && g < lg)) j = KTOP - 1;
                            else continue;
                        }
                        while (j > 0 && (key[j-1] > d2v || (key[j-1] == d2v && gi[j-1] > g))) {
                            key[j] = key[j-1]; gi[j] = gi[j-1]; --j;
                        }
                        key[j] = d2v; gi[j] = g;
                    }
                }
            }
        }

        if (act) {
            const size_t base = (size_t)q * KTOP;
            #pragma unroll
            for (int kk = 0; kk < KTOP / 4; ++kk) {
                float4 fi, fw, fm;
                float* pi = (float*)&fi; float* pw = (float*)&fw; float* pm = (float*)&fm;
                #pragma unroll
                for (int j = 0; j < 4; ++j) {
                    const int k = kk * 4 + j;
                    const bool v = (k < cnt);
                    pi[j] = v ? (float)gi[k] : -1.0f;
                    pw[j] = v ? key[k] : 0.0f;
                    pm[j] = v ? 1.0f : 0.0f;
                }
                *(float4*)&idxb[base + kk*4] = fi;
                *(float4*)&wb[base + kk*4]   = fw;
                *(float4*)&mb[base + kk*4]   = fm;
            }
        }
    }
}

extern "C" void kernel_launch(void* const* d_in, const int* in_sizes, int n_in,
                              void* d_out, int out_size, void* d_ws, size_t ws_size,
                              hipStream_t stream)
{
    const int*   vox   = (const int*)d_in[0];
    const float* mu    = (const float*)d_in[1];
    const float* scale = (const float*)d_in[2];
    const float* pcr   = (const float*)d_in[3];
    float* out = (float*)d_out;

    const int M = in_sizes[0] / 4;
    const int N = in_sizes[1] / 3;

    // ws layout (256-aligned)
    char* ws = (char*)d_ws;
    const size_t entries_cap = (size_t)N * 49 + 64;
    size_t o = 0;
    float* params = (float*)(ws + o);                    o += ((size_t)N * 32 + 255) & ~(size_t)255;
    unsigned long long* cellinfo = (unsigned long long*)(ws + o); o += ((size_t)N * 8 + 255) & ~(size_t)255;
    unsigned short* entries = (unsigned short*)(ws + o); o += (entries_cap * 2 + 255) & ~(size_t)255;
    int* qids  = (int*)(ws + o);                         o += ((size_t)M * 4 + 255) & ~(size_t)255;
    int* cnts  = (int*)(ws + o);                         o += (2 * NCELL * 4 + 255) & ~(size_t)255;
    int* goff  = (int*)(ws + o);                         o += ((NCELL + 1) * 4 + 255) & ~(size_t)255;
    int* qoff  = (int*)(ws + o);                         o += ((NCELL + 1) * 4 + 255) & ~(size_t)255;
    int* gcur  = (int*)(ws + o);                         o += (NCELL * 4 + 255) & ~(size_t)255;
    int* qcur  = (int*)(ws + o);                         o += (NCELL * 4 + 255) & ~(size_t)255;
    int* gcnt = cnts;
    int* qcnt = cnts + NCELL;

    const int GB = (N + 255) / 256;
    const int QB = (M + 255) / 256;

    hipLaunchKernelGGL(k_zero, dim3(2), dim3(1024), 0, stream, cnts);
    hipLaunchKernelGGL(k_count, dim3(GB + QB), dim3(256), 0, stream,
                       mu, scale, vox, pcr, params, cellinfo, gcnt, qcnt, out, N, M, GB);
    hipLaunchKernelGGL(k_prefix, dim3(1), dim3(64), 0, stream,
                       gcnt, qcnt, goff, qoff, gcur, qcur);
    hipLaunchKernelGGL(k_scatter, dim3(GB + QB), dim3(256), 0, stream,
                       cellinfo, vox, pcr, gcur, qcur, entries, qids, N, M, GB);
    hipLaunchKernelGGL(k_scan, dim3(NCELL), dim3(64), 0, stream,
                       vox, pcr, params, entries, goff, qids, qoff, out, M);
}

// Round 7
// 149.149 us; speedup vs baseline: 1.4466x; 1.4466x over previous
//
#include <hip/hip_runtime.h>

#define KTOP 64
#define GX   32
#define NCELL (GX*GX)
#define CSF  3.2f
#define X0F  -51.2f
#define GCAP 384        // gaussian-entry capacity per cell (avg ~72, sigma ~8)
#define QCAP 128        // query capacity per cell (avg ~48, sigma ~7)
#define TR   128        // param rows staged per tile (per-wave LDS)

// Anti-contraction barrier: force f32 rounding points to match the reference.
#define BAR(x) asm volatile("" : "+v"(x))

// -------- binning helpers (f64, conservative margins; proven rounds 4-6) -----
__device__ inline void g_reach_cells(float s0, float s1, float s2,
                                     float m0, float m1,
                                     int& cx0, int& cx1, int& cy0, int& cy1,
                                     double& mux, double& muy, double& reach2)
{
    const double ss0 = (double)s0 * (double)s0 + 1e-8;
    const double ss1 = (double)s1 * (double)s1 + 1e-8;
    const double ss2 = (double)s2 * (double)s2 + 1e-8;
    double smax = ss0 > ss1 ? ss0 : ss1; smax = smax > ss2 ? smax : ss2;
    const double sum = ss0 + ss1 + ss2;
    reach2 = 9.0 * smax * sum * 1.0005 + 0.5;   // covers f32 d2/r2 rounding
    const double reach = sqrt(reach2);
    mux = (double)m0; muy = (double)m1;
    cx0 = (int)floor((mux - reach - (double)X0F) / (double)CSF);
    cx1 = (int)floor((mux + reach - (double)X0F) / (double)CSF);
    cy0 = (int)floor((muy - reach - (double)X0F) / (double)CSF);
    cy1 = (int)floor((muy + reach - (double)X0F) / (double)CSF);
    cx0 = cx0 < 0 ? 0 : cx0;  cy0 = cy0 < 0 ? 0 : cy0;
    cx1 = cx1 > GX-1 ? GX-1 : cx1;  cy1 = cy1 > GX-1 ? GX-1 : cy1;
}

__device__ inline bool cell_hits(int cx, int cy, double mux, double muy, double reach2)
{
    const double lx = (double)X0F + (double)cx * (double)CSF - 1e-3;
    const double hx = lx + (double)CSF + 2e-3;
    const double ly = (double)X0F + (double)cy * (double)CSF - 1e-3;
    const double hy = ly + (double)CSF + 2e-3;
    double dx = 0.0, dy = 0.0;
    if (mux < lx) dx = lx - mux; else if (mux > hx) dx = mux - hx;
    if (muy < ly) dy = ly - muy; else if (muy > hy) dy = muy - hy;
    return dx*dx + dy*dy <= reach2;
}

__device__ inline void q_center(int ix, int iy, int iz, float pc0, float pc1, float pc2,
                                float& qx, float& qy, float& qz)
{
    float tx = ((float)ix + 0.5f) * 0.2f; BAR(tx);
    float ty = ((float)iy + 0.5f) * 0.2f; BAR(ty);
    float tz = ((float)iz + 0.5f) * 0.2f; BAR(tz);
    qx = pc0 + tx;  qy = pc1 + ty;  qz = pc2 + tz;
}

__device__ inline int q_cell(float qx, float qy)
{
    int cx = (int)floorf((qx - X0F) * (1.0f / CSF));
    int cy = (int)floorf((qy - X0F) * (1.0f / CSF));
    cx = cx < 0 ? 0 : (cx > GX-1 ? GX-1 : cx);
    cy = cy < 0 ? 0 : (cy > GX-1 ? GX-1 : cy);
    return cy * GX + cx;
}

// -------- kernel 1: zero both counter arrays --------
__global__ __launch_bounds__(1024)
void k_zero(int* __restrict__ cnts)
{
    cnts[blockIdx.x * 1024 + threadIdx.x] = 0;
}

// -------- kernel 2: params + direct binning (fixed-capacity bins, no prefix) --------
__global__ __launch_bounds__(256)
void k_fill(const float* __restrict__ mu, const float* __restrict__ scale,
            const int* __restrict__ vox, const float* __restrict__ pcr,
            float* __restrict__ params,
            int* __restrict__ gcnt, int* __restrict__ qcnt,
            unsigned short* __restrict__ entries, int* __restrict__ qids,
            float* __restrict__ out, int N, int M, int GB)
{
    const int b = blockIdx.x;
    if (b < GB) {
        const int g = b * 256 + threadIdx.x;
        if (g >= N) return;
        const float s0 = scale[3*g+0], s1 = scale[3*g+1], s2 = scale[3*g+2];
        const float m0 = mu[3*g+0],    m1 = mu[3*g+1],    m2 = mu[3*g+2];
        // proven bit-exact f32 param derivation (rounds 2-6)
        float s0s = s0 * s0; BAR(s0s);
        float s1s = s1 * s1; BAR(s1s);
        float s2s = s2 * s2; BAR(s2s);
        float d0 = s0s + 1e-8f;
        float d1 = s1s + 1e-8f;
        float dd2 = s2s + 1e-8f;
        float i0 = 1.0f / d0;
        float i1 = 1.0f / d1;
        float i2 = 1.0f / dd2;
        float mi0 = m0 * i0; BAR(mi0);
        float mi1 = m1 * i1; BAR(mi1);
        float mi2 = m2 * i2; BAR(mi2);
        float p0 = m0 * mi0; BAR(p0);
        float p1 = m1 * mi1; BAR(p1);
        float p2 = m2 * mi2; BAR(p2);
        float mt = (p0 + p1) + p2;
        float rs = (s0s + s1s) + s2s;
        float r2 = 9.0f * rs;
        *(float4*)&params[(size_t)g*8]     = make_float4(i0, i1, i2, mi0);
        *(float4*)&params[(size_t)g*8 + 4] = make_float4(mi1, mi2, mt, r2);

        int cx0, cx1, cy0, cy1; double mux, muy, reach2;
        g_reach_cells(s0, s1, s2, m0, m1, cx0, cx1, cy0, cy1, mux, muy, reach2);
        for (int cy = cy0; cy <= cy1; ++cy)
            for (int cx = cx0; cx <= cx1; ++cx)
                if (cell_hits(cx, cy, mux, muy, reach2)) {
                    const int cell = cy*GX + cx;
                    int pos = atomicAdd(&gcnt[cell], 1);
                    if (pos < GCAP) entries[(size_t)cell * GCAP + pos] = (unsigned short)g;
                }
    } else {
        const int q = (b - GB) * 256 + threadIdx.x;
        if (q >= M) return;
        int4 c = ((const int4*)vox)[q];   // (b, z, y, x)
        float qx, qy, qz;
        q_center(c.w, c.z, c.y, pcr[0], pcr[1], pcr[2], qx, qy, qz);
        out[3*(size_t)q + 0] = qx;
        out[3*(size_t)q + 1] = qy;
        out[3*(size_t)q + 2] = qz;
        const int cell = q_cell(qx, qy);
        int pos = atomicAdd(&qcnt[cell], 1);
        if (pos < QCAP) qids[(size_t)cell * QCAP + pos] = q;
    }
}

// -------- kernel 3: one wave per cell; LDS-resident top-K (no scratch) --------
__global__ __launch_bounds__(64)
void k_scan(const int* __restrict__ vox, const float* __restrict__ pcr,
            const float* __restrict__ params,
            const unsigned short* __restrict__ entries, const int* __restrict__ gcnt,
            const int* __restrict__ qids, const int* __restrict__ qcnt,
            float* __restrict__ out, int M)
{
    __shared__ float Pa[TR][8];          // 4 KB staged param rows
    __shared__ int   Pg[TR];             // 0.5 KB
    __shared__ float keyL[KTOP][64];     // 16 KB  [slot][lane] — 2-way banks (free)
    __shared__ int   giL [KTOP][64];     // 16 KB

    const int cell = blockIdx.x;
    const int l = threadIdx.x;
    const int nq_cell = qcnt[cell] < QCAP ? qcnt[cell] : QCAP;
    if (nq_cell == 0) return;
    int L = gcnt[cell]; L = L < GCAP ? L : GCAP;
    const unsigned short* ebase = entries + (size_t)cell * GCAP;
    const int* qbase = qids + (size_t)cell * QCAP;

    const float pc0 = pcr[0], pc1 = pcr[1], pc2 = pcr[2];

    float* idxb = out + 3 * (size_t)M;
    float* wb   = idxb + (size_t)M * KTOP;
    float* mb   = wb   + (size_t)M * KTOP;

    for (int q0 = 0; q0 < nq_cell; q0 += 64) {
        const int nq = (nq_cell - q0 < 64) ? (nq_cell - q0) : 64;
        const bool act = (l < nq);
        const int q = act ? qbase[q0 + l] : 0;

        float qx = 0.f, qy = 0.f, qz = 0.f;
        if (act) {
            int4 c = ((const int4*)vox)[q];
            q_center(c.w, c.z, c.y, pc0, pc1, pc2, qx, qy, qz);
        }
        float qx2 = qx * qx; BAR(qx2);
        float qy2 = qy * qy; BAR(qy2);
        float qz2 = qz * qz; BAR(qz2);

        int cnt = 0;

        for (int t0 = 0; t0 < L; t0 += TR) {
            const int rows = (L - t0 < TR) ? (L - t0) : TR;
            __syncthreads();   // single-wave barrier: orders LDS reuse (~free)
            for (int r = l; r < rows * 2; r += 64) {
                const int row = r >> 1, half = r & 1;
                const int g = ebase[t0 + row];
                float4 v = *(const float4*)&params[(size_t)g * 8 + half * 4];
                *(float4*)&Pa[row][half * 4] = v;
                if (half == 0) Pg[row] = g;
            }
            __syncthreads();

            if (act) {
                for (int i = 0; i < rows; ++i) {
                    const float4 pa = *(const float4*)&Pa[i][0];
                    const float4 pb = *(const float4*)&Pa[i][4];
                    // proven bit-exact d2 (rounds 2-6)
                    float t1 = __builtin_fmaf(qz2, pa.z, __builtin_fmaf(qy2, pa.y, qx2 * pa.x));
                    float t2 = __builtin_fmaf(qz,  pb.y, __builtin_fmaf(qy,  pb.x, qx  * pa.w));
                    const float d2v = (t1 - 2.0f * t2) + pb.z;
                    if (d2v <= pb.w) {
                        const int g = Pg[i];
                        int j;
                        if (cnt < KTOP) {
                            j = cnt++;
                        } else {
                            const float lk = keyL[KTOP-1][l];
                            const int   lg = giL [KTOP-1][l];
                            if (d2v < lk || (d2v == lk && g < lg)) j = KTOP - 1;
                            else continue;
                        }
                        // lex (d2, g) sorted insert, LDS-resident
                        while (j > 0) {
                            const float pk = keyL[j-1][l];
                            const int   pg = giL [j-1][l];
                            if (pk > d2v || (pk == d2v && pg > g)) {
                                keyL[j][l] = pk; giL[j][l] = pg; --j;
                            } else break;
                        }
                        keyL[j][l] = d2v; giL[j][l] = g;
                    }
                }
            }
        }

        if (act) {
            const size_t base = (size_t)q * KTOP;
            #pragma unroll
            for (int kk = 0; kk < KTOP / 4; ++kk) {
                float4 fi, fw, fm;
                float* pi = (float*)&fi; float* pw = (float*)&fw; float* pm = (float*)&fm;
                #pragma unroll
                for (int j = 0; j < 4; ++j) {
                    const int k = kk * 4 + j;
                    const bool v = (k < cnt);
                    pi[j] = v ? (float)giL[k][l] : -1.0f;
                    pw[j] = v ? keyL[k][l] : 0.0f;
                    pm[j] = v ? 1.0f : 0.0f;
                }
                *(float4*)&idxb[base + kk*4] = fi;
                *(float4*)&wb[base + kk*4]   = fw;
                *(float4*)&mb[base + kk*4]   = fm;
            }
        }
    }
}

extern "C" void kernel_launch(void* const* d_in, const int* in_sizes, int n_in,
                              void* d_out, int out_size, void* d_ws, size_t ws_size,
                              hipStream_t stream)
{
    const int*   vox   = (const int*)d_in[0];
    const float* mu    = (const float*)d_in[1];
    const float* scale = (const float*)d_in[2];
    const float* pcr   = (const float*)d_in[3];
    float* out = (float*)d_out;

    const int M = in_sizes[0] / 4;
    const int N = in_sizes[1] / 3;

    // ws layout (256-aligned)
    char* ws = (char*)d_ws;
    size_t o = 0;
    float* params = (float*)(ws + o);                    o += ((size_t)N * 32 + 255) & ~(size_t)255;
    unsigned short* entries = (unsigned short*)(ws + o); o += ((size_t)NCELL * GCAP * 2 + 255) & ~(size_t)255;
    int* qids  = (int*)(ws + o);                         o += ((size_t)NCELL * QCAP * 4 + 255) & ~(size_t)255;
    int* cnts  = (int*)(ws + o);                         o += (2 * NCELL * 4 + 255) & ~(size_t)255;
    int* gcnt = cnts;
    int* qcnt = cnts + NCELL;

    const int GB = (N + 255) / 256;
    const int QB = (M + 255) / 256;

    hipLaunchKernelGGL(k_zero, dim3(2), dim3(1024), 0, stream, cnts);
    hipLaunchKernelGGL(k_fill, dim3(GB + QB), dim3(256), 0, stream,
                       mu, scale, vox, pcr, params, gcnt, qcnt, entries, qids, out, N, M, GB);
    hipLaunchKernelGGL(k_scan, dim3(NCELL), dim3(64), 0, stream,
                       vox, pcr, params, entries, gcnt, qids, qcnt, out, M);
}